// Round 5
// baseline (1335.338 us; speedup 1.0000x reference)
//
#include <hip/hip_runtime.h>
#include <hip/hip_bf16.h>

#define N_NODES 100000
#define N_EDGES 1600000
#define IN_DIM 48
#define OUT_DIM 128
#define K1 144                // 3*IN_DIM
#define NSEG (2 * N_NODES)    // 200000 segments (node x {mi,mo})
#define SEGS_PER_BKT 256
#define NBKT 782              // ceil(NSEG / 256)
#define SUB 16                // XCD-local sub-buckets per bucket
#define BCAP 352              // capacity per (bucket,sub): mean 256 + 6 sigma

typedef unsigned short u16;
typedef __attribute__((ext_vector_type(8))) short short8;
typedef __attribute__((ext_vector_type(4))) float f32x4;

// round-to-nearest-even f32 -> bf16 bits
static __device__ __forceinline__ u16 f2bf(float f) {
  unsigned u = __float_as_uint(f);
  unsigned r = (u + 0x7fffu + ((u >> 16) & 1u)) >> 16;
  return (u16)r;
}
static __device__ __forceinline__ float bf2f(u16 u) {
  return __uint_as_float(((unsigned)u) << 16);
}

// ---------------------------------------------------------------------------
// Stage 0a: weight conversion fp32 -> bf16
// ---------------------------------------------------------------------------
__global__ __launch_bounds__(256) void prep_w_kernel(
    const float* __restrict__ W1, const float* __restrict__ W2,
    u16* __restrict__ W1b, u16* __restrict__ W2b)
{
  int i = blockIdx.x * 256 + threadIdx.x;
  if (i < OUT_DIM * K1) {
    W1b[i] = f2bf(W1[i]);
  } else if (i < OUT_DIM * K1 + OUT_DIM * OUT_DIM) {
    int j = i - OUT_DIM * K1;
    W2b[j] = f2bf(W2[j]);
  }
}

// Stage 0b: x conversion fp32 -> bf16 (compact [node][48])
__global__ __launch_bounds__(256) void prep_x_kernel(
    const float* __restrict__ x, u16* __restrict__ xb)
{
  int i = blockIdx.x * 256 + threadIdx.x;
  if (i < N_NODES * IN_DIM) xb[i] = f2bf(x[i]);
}

// ---------------------------------------------------------------------------
// Pass 1: bucket scatter. One thread per edge -> 2 records.
// record.x = src | (seg_low << 20), record.y = fp32 weight bits.
// Sub-bucket chosen from blockIdx so writers share an XCD (full-line fills).
// Cursors padded to one per 64B line.
// ---------------------------------------------------------------------------
__global__ __launch_bounds__(256) void bucket_scatter_kernel(
    const int* __restrict__ eidx, const float* __restrict__ ea,
    int* __restrict__ cursors, int2* __restrict__ bkt)
{
  int e = blockIdx.x * 256 + threadIdx.x;
  int sub = (blockIdx.x & 7) + 8 * ((blockIdx.x >> 3) & 1);
  if (e >= N_EDGES) return;
  int row = eidx[e];
  int col = eidx[N_EDGES + e];
  int w = __float_as_int(ea[e]);
  {
    int seg = col * 2;                       // dir0 (mi): dst=col, src=row
    int sb  = (seg >> 8) * SUB + sub;
    int slot = atomicAdd(&cursors[sb * 16], 1);
    if (slot < BCAP)
      bkt[(size_t)sb * BCAP + slot] = make_int2(row | ((seg & 255) << 20), w);
  }
  {
    int seg = row * 2 + 1;                   // dir1 (mo): dst=row, src=col
    int sb  = (seg >> 8) * SUB + sub;
    int slot = atomicAdd(&cursors[sb * 16], 1);
    if (slot < BCAP)
      bkt[(size_t)sb * BCAP + slot] = make_int2(col | ((seg & 255) << 20), w);
  }
}

// ---------------------------------------------------------------------------
// Pass 2: bucket gather. One block per bucket; fp32 acc for 256 segments in
// LDS ([256][49] -> both ds_add lanes and writeout are conflict-free).
// Wave-per-record, lanes 0..47 = dims, unroll-2 for MLP of x-row loads.
// ---------------------------------------------------------------------------
__global__ __launch_bounds__(256) void bucket_gather_kernel(
    const int2* __restrict__ bkt, const int* __restrict__ cursors,
    const u16* __restrict__ xb, u16* __restrict__ Mseg)
{
  __shared__ float acc[SEGS_PER_BKT][49];
  const int b = blockIdx.x;
  const int wave = threadIdx.x >> 6;
  const int lane = threadIdx.x & 63;
  const bool act = lane < IN_DIM;

  for (int i = threadIdx.x; i < SEGS_PER_BKT * 49; i += 256)
    ((float*)acc)[i] = 0.f;
  __syncthreads();

  for (int s = 0; s < SUB; ++s) {
    const int sb = b * SUB + s;
    int cnt = cursors[sb * 16];
    if (cnt > BCAP) cnt = BCAP;
    const int2* recs = bkt + (size_t)sb * BCAP;
    int j = wave;
    for (; j + 8 <= cnt; j += 8) {          // two records per wave per iter
      int2 r0 = recs[j];
      int2 r1 = recs[j + 4];
      if (act) {
        float v0 = bf2f(xb[(r0.x & 0xFFFFF) * IN_DIM + lane]);
        float v1 = bf2f(xb[(r1.x & 0xFFFFF) * IN_DIM + lane]);
        atomicAdd(&acc[r0.x >> 20][lane], v0 * __int_as_float(r0.y));
        atomicAdd(&acc[r1.x >> 20][lane], v1 * __int_as_float(r1.y));
      }
    }
    for (; j < cnt; j += 4) {
      int2 r = recs[j];
      if (act) {
        float v = bf2f(xb[(r.x & 0xFFFFF) * IN_DIM + lane]);
        atomicAdd(&acc[r.x >> 20][lane], v * __int_as_float(r.y));
      }
    }
  }
  __syncthreads();

  // writeout: thread t -> segment b*256+t, 96B contiguous bf16
  const int t = threadIdx.x;
  const int seg = b * SEGS_PER_BKT + t;
  if (seg < NSEG) {
#pragma unroll
    for (int d = 0; d < IN_DIM; d += 8) {
      short8 v;
#pragma unroll
      for (int k = 0; k < 8; ++k) v[k] = (short)f2bf(acc[t][d + k]);
      *(short8*)(Mseg + (size_t)seg * IN_DIM + d) = v;
    }
  }
}

// ---------------------------------------------------------------------------
// Stage 2: fused 2-layer MLP with MFMA 16x16x32 bf16.  (unchanged)
// ---------------------------------------------------------------------------
static __device__ __forceinline__ short8 loadM(
    const u16* __restrict__ Mseg, const u16* __restrict__ xb, int m, int k)
{
  short8 r = {0, 0, 0, 0, 0, 0, 0, 0};
  if (k < 96) {
    r = *(const short8*)(Mseg + m * 96 + k);
  } else if (k < K1) {
    r = *(const short8*)(xb + m * IN_DIM + (k - 96));
  }
  return r;
}

__global__ __launch_bounds__(256) void mlp_kernel(
    const u16* __restrict__ Mseg, const u16* __restrict__ xb,
    const u16* __restrict__ W1b, const float* __restrict__ b1,
    const u16* __restrict__ W2b, const float* __restrict__ b2,
    float* __restrict__ out)
{
  __shared__ __align__(16) u16 hbuf[4][32][136];
  const int wave = threadIdx.x >> 6;
  const int lane = threadIdx.x & 63;
  const int col  = lane & 15;
  const int quad = lane >> 4;
  const int kq   = quad * 8;
  const int nodeBase = (blockIdx.x * 4 + wave) * 32;

  const int ma0 = min(nodeBase + col,      N_NODES - 1);
  const int ma1 = min(nodeBase + 16 + col, N_NODES - 1);

  f32x4 acc[2][8];
#pragma unroll
  for (int mt = 0; mt < 2; ++mt)
#pragma unroll
    for (int nt = 0; nt < 8; ++nt) acc[mt][nt] = (f32x4){0.f, 0.f, 0.f, 0.f};

#pragma unroll
  for (int ks = 0; ks < 5; ++ks) {
    const int k = ks * 32 + kq;
    short8 a0 = loadM(Mseg, xb, ma0, k);
    short8 a1 = loadM(Mseg, xb, ma1, k);
#pragma unroll
    for (int nt = 0; nt < 8; ++nt) {
      short8 b = {0, 0, 0, 0, 0, 0, 0, 0};
      if (k < K1)
        b = *(const short8*)(W1b + (nt * 16 + col) * K1 + k);
      acc[0][nt] = __builtin_amdgcn_mfma_f32_16x16x32_bf16(a0, b, acc[0][nt], 0, 0, 0);
      acc[1][nt] = __builtin_amdgcn_mfma_f32_16x16x32_bf16(a1, b, acc[1][nt], 0, 0, 0);
    }
  }

#pragma unroll
  for (int mt = 0; mt < 2; ++mt)
#pragma unroll
    for (int nt = 0; nt < 8; ++nt) {
      const int n = nt * 16 + col;
      const float bb = b1[n];
#pragma unroll
      for (int rg = 0; rg < 4; ++rg) {
        const int rowl = mt * 16 + quad * 4 + rg;
        hbuf[wave][rowl][n] = f2bf(tanhf(acc[mt][nt][rg] + bb));
      }
    }
  __syncthreads();

  f32x4 acc2[2][8];
#pragma unroll
  for (int mt = 0; mt < 2; ++mt)
#pragma unroll
    for (int nt = 0; nt < 8; ++nt) acc2[mt][nt] = (f32x4){0.f, 0.f, 0.f, 0.f};

#pragma unroll
  for (int ks = 0; ks < 4; ++ks) {
    const int k = ks * 32 + kq;
    short8 a0 = *(const short8*)&hbuf[wave][col][k];
    short8 a1 = *(const short8*)&hbuf[wave][16 + col][k];
#pragma unroll
    for (int nt = 0; nt < 8; ++nt) {
      short8 b = *(const short8*)(W2b + (nt * 16 + col) * OUT_DIM + k);
      acc2[0][nt] = __builtin_amdgcn_mfma_f32_16x16x32_bf16(a0, b, acc2[0][nt], 0, 0, 0);
      acc2[1][nt] = __builtin_amdgcn_mfma_f32_16x16x32_bf16(a1, b, acc2[1][nt], 0, 0, 0);
    }
  }

#pragma unroll
  for (int mt = 0; mt < 2; ++mt)
#pragma unroll
    for (int nt = 0; nt < 8; ++nt) {
      const int n = nt * 16 + col;
      const float bb = b2[n];
#pragma unroll
      for (int rg = 0; rg < 4; ++rg) {
        const int node = nodeBase + mt * 16 + quad * 4 + rg;
        if (node < N_NODES)
          out[node * OUT_DIM + n] = tanhf(acc2[mt][nt][rg] + bb);
      }
    }
}

extern "C" void kernel_launch(void* const* d_in, const int* in_sizes, int n_in,
                              void* d_out, int out_size, void* d_ws, size_t ws_size,
                              hipStream_t stream) {
  const float* x   = (const float*)d_in[0];
  const int* eidx  = (const int*)d_in[1];
  const float* ea  = (const float*)d_in[2];
  const float* W1  = (const float*)d_in[3];
  const float* b1  = (const float*)d_in[4];
  const float* W2  = (const float*)d_in[5];
  const float* b2  = (const float*)d_in[6];
  float* out = (float*)d_out;

  // workspace layout (16B-aligned):
  char* p = (char*)d_ws;
  u16* Mseg    = (u16*)p;  p += (size_t)NSEG * IN_DIM * 2;            // 19.2 MB
  u16* xb      = (u16*)p;  p += (size_t)N_NODES * IN_DIM * 2;         //  9.6 MB
  u16* W1b     = (u16*)p;  p += OUT_DIM * K1 * 2;
  u16* W2b     = (u16*)p;  p += OUT_DIM * OUT_DIM * 2;
  int* cursors = (int*)p;  p += (size_t)NBKT * SUB * 16 * 4;          //  0.8 MB
  int2* bkt    = (int2*)p; p += (size_t)NBKT * SUB * BCAP * 8;        // 33.6 MB

  // zero the padded cursors
  hipMemsetAsync(cursors, 0, (size_t)NBKT * SUB * 16 * 4, stream);

  // conversions
  int prep_elems = OUT_DIM * K1 + OUT_DIM * OUT_DIM;
  prep_w_kernel<<<(prep_elems + 255) / 256, 256, 0, stream>>>(W1, W2, W1b, W2b);
  prep_x_kernel<<<(N_NODES * IN_DIM + 255) / 256, 256, 0, stream>>>(x, xb);

  // pass 1: bucket scatter (per-edge threads)
  bucket_scatter_kernel<<<(N_EDGES + 255) / 256, 256, 0, stream>>>(
      eidx, ea, cursors, bkt);

  // pass 2: bucket gather into Mseg
  bucket_gather_kernel<<<NBKT, 256, 0, stream>>>(bkt, cursors, xb, Mseg);

  // MLP: 128 nodes per 256-thread block
  int nblocks = (N_NODES + 127) / 128;
  mlp_kernel<<<nblocks, 256, 0, stream>>>(Mseg, xb, W1b, b1, W2b, b2, out);
}

// Round 6
// 737.561 us; speedup vs baseline: 1.8105x; 1.8105x over previous
//
#include <hip/hip_runtime.h>
#include <hip/hip_bf16.h>

#define N_NODES 100000
#define N_EDGES 1600000
#define IN_DIM 48
#define OUT_DIM 128
#define K1 144                 // 3*IN_DIM
#define NSEG (2 * N_NODES)     // 200000 segments (node x {mi,mo})
#define NMSG (2 * N_EDGES)     // 3.2M directed messages
#define NSUB 16                // XCD-local sub-cursors per segment
#define NSUBSEG (NSEG * NSUB)  // 3,200,000 sub-segments (multiple of 1024)
#define NCHUNK (NSUBSEG / 1024) // 3125 scan chunks

typedef unsigned short u16;
typedef __attribute__((ext_vector_type(8))) short short8;
typedef __attribute__((ext_vector_type(4))) float f32x4;

// round-to-nearest-even f32 -> bf16 bits
static __device__ __forceinline__ u16 f2bf(float f) {
  unsigned u = __float_as_uint(f);
  unsigned r = (u + 0x7fffu + ((u >> 16) & 1u)) >> 16;
  return (u16)r;
}
static __device__ __forceinline__ float bf2f(u16 u) {
  return __uint_as_float(((unsigned)u) << 16);
}

// sub-bucket from blockIdx: blocks with equal (blockIdx % 8) tend to share an
// XCD (round-robin dispatch heuristic); 16 subs = 2 rotations.
static __device__ __forceinline__ int sub_of_block(int b) {
  return (b & 7) + 8 * ((b >> 3) & 1);
}

// ---------------------------------------------------------------------------
// Stage 0: dtype conversions (fp32 -> bf16)
// ---------------------------------------------------------------------------
__global__ __launch_bounds__(256) void prep_w_kernel(
    const float* __restrict__ W1, const float* __restrict__ W2,
    u16* __restrict__ W1b, u16* __restrict__ W2b)
{
  int i = blockIdx.x * 256 + threadIdx.x;
  if (i < OUT_DIM * K1) {
    W1b[i] = f2bf(W1[i]);
  } else if (i < OUT_DIM * K1 + OUT_DIM * OUT_DIM) {
    int j = i - OUT_DIM * K1;
    W2b[j] = f2bf(W2[j]);
  }
}

__global__ __launch_bounds__(256) void prep_x_kernel(
    const float* __restrict__ x, u16* __restrict__ xb)
{
  int i = blockIdx.x * 256 + threadIdx.x;
  if (i < N_NODES * IN_DIM) xb[i] = f2bf(x[i]);
}

// ---------------------------------------------------------------------------
// CSR build over sub-segment keys seg*16+sub.
//   dir0 (mi): dst=col, src=row    dir1 (mo): dst=row, src=col
// ---------------------------------------------------------------------------
__global__ __launch_bounds__(256) void hist_kernel(
    const int* __restrict__ eidx, int* __restrict__ counts)
{
  int e = blockIdx.x * 256 + threadIdx.x;
  if (e >= N_EDGES) return;
  int sub = sub_of_block(blockIdx.x);
  int row = eidx[e];
  int col = eidx[N_EDGES + e];
  atomicAdd(&counts[(col * 2 + 0) * NSUB + sub], 1);
  atomicAdd(&counts[(row * 2 + 1) * NSUB + sub], 1);
}

// per-chunk (1024 elems) exclusive scan; chunk totals to wgsums
__global__ __launch_bounds__(256) void scan1_kernel(
    const int* __restrict__ counts, int* __restrict__ offsets,
    int* __restrict__ wgsums)
{
  __shared__ int sh[256];
  int base = blockIdx.x * 1024;
  int4 v = ((const int4*)(counts + base))[threadIdx.x];
  int s0 = v.x, s1 = s0 + v.y, s2 = s1 + v.z, s3 = s2 + v.w;
  sh[threadIdx.x] = s3;
  __syncthreads();
#pragma unroll
  for (int off = 1; off < 256; off <<= 1) {
    int t = (threadIdx.x >= off) ? sh[threadIdx.x - off] : 0;
    __syncthreads();
    sh[threadIdx.x] += t;
    __syncthreads();
  }
  int excl = threadIdx.x ? sh[threadIdx.x - 1] : 0;
  int4 o;
  o.x = excl; o.y = excl + s0; o.z = excl + s1; o.w = excl + s2;
  ((int4*)(offsets + base))[threadIdx.x] = o;
  if (threadIdx.x == 255) wgsums[blockIdx.x] = sh[255];
}

// single-block exclusive scan of NCHUNK (3125) chunk totals, 256 at a time
__global__ __launch_bounds__(256) void scan2_kernel(int* __restrict__ wgsums)
{
  __shared__ int sh[256];
  int carry = 0;
  for (int base = 0; base < NCHUNK; base += 256) {
    int idx = base + threadIdx.x;
    int v = (idx < NCHUNK) ? wgsums[idx] : 0;
    sh[threadIdx.x] = v;
    __syncthreads();
#pragma unroll
    for (int off = 1; off < 256; off <<= 1) {
      int t = (threadIdx.x >= off) ? sh[threadIdx.x - off] : 0;
      __syncthreads();
      sh[threadIdx.x] += t;
      __syncthreads();
    }
    int excl = carry + (threadIdx.x ? sh[threadIdx.x - 1] : 0);
    if (idx < NCHUNK) wgsums[idx] = excl;
    carry += sh[255];
    __syncthreads();
  }
}

// add chunk prefix (offsets doubles as the fill cursor array)
__global__ __launch_bounds__(256) void scan3_kernel(
    int* __restrict__ offsets, const int* __restrict__ wgsums)
{
  int add = wgsums[blockIdx.x];
  int base = blockIdx.x * 1024;
  int4 o = ((const int4*)(offsets + base))[threadIdx.x];
  o.x += add; o.y += add; o.z += add; o.w += add;
  ((int4*)(offsets + base))[threadIdx.x] = o;
}

// fill: bump the offsets (cursor) array; same sub as hist for the same edge.
// Consecutive slots of a sub-range are written by same-XCD blocks -> CSR
// lines fill completely before writeback (no partial-line amplification).
// Post-fill invariant: offsets[i] == orig_offsets[i+1].
__global__ __launch_bounds__(256) void fill_kernel(
    const int* __restrict__ eidx, const float* __restrict__ ea,
    int* __restrict__ offsets, int2* __restrict__ csr)
{
  int e = blockIdx.x * 256 + threadIdx.x;
  if (e >= N_EDGES) return;
  int sub = sub_of_block(blockIdx.x);
  int row = eidx[e];
  int col = eidx[N_EDGES + e];
  int w = __float_as_int(ea[e]);
  int s0 = atomicAdd(&offsets[(col * 2 + 0) * NSUB + sub], 1);
  csr[s0] = make_int2(row, w);
  int s1 = atomicAdd(&offsets[(row * 2 + 1) * NSUB + sub], 1);
  csr[s1] = make_int2(col, w);
}

// ---------------------------------------------------------------------------
// Gather (round-4 design): one wave per segment; lanes 0..47 = dims.
// Unroll-4, 4 independent accumulators -> 4 x-row loads in flight.
// beg/end derived from the post-fill cursor state.
// Mseg layout: [node][0..47]=mi, [48..95]=mo (bf16)
// ---------------------------------------------------------------------------
__global__ __launch_bounds__(256) void gather_kernel(
    const int2* __restrict__ csr, const int* __restrict__ offs,
    const u16* __restrict__ xb, u16* __restrict__ Mseg)
{
  int seg = blockIdx.x * 4 + (threadIdx.x >> 6);
  int lane = threadIdx.x & 63;
  int beg = (seg == 0) ? 0 : offs[seg * NSUB - 1];
  int end = offs[seg * NSUB + NSUB - 1];
  bool act = lane < IN_DIM;
  float a0 = 0.f, a1 = 0.f, a2 = 0.f, a3 = 0.f;
  int j = beg;
  for (; j + 4 <= end; j += 4) {
    int2 r0 = csr[j + 0];
    int2 r1 = csr[j + 1];
    int2 r2 = csr[j + 2];
    int2 r3 = csr[j + 3];
    float v0 = 0.f, v1 = 0.f, v2 = 0.f, v3 = 0.f;
    if (act) {
      v0 = bf2f(xb[r0.x * IN_DIM + lane]);
      v1 = bf2f(xb[r1.x * IN_DIM + lane]);
      v2 = bf2f(xb[r2.x * IN_DIM + lane]);
      v3 = bf2f(xb[r3.x * IN_DIM + lane]);
    }
    a0 = fmaf(v0, __int_as_float(r0.y), a0);
    a1 = fmaf(v1, __int_as_float(r1.y), a1);
    a2 = fmaf(v2, __int_as_float(r2.y), a2);
    a3 = fmaf(v3, __int_as_float(r3.y), a3);
  }
  for (; j < end; ++j) {
    int2 r = csr[j];
    float v = 0.f;
    if (act) v = bf2f(xb[r.x * IN_DIM + lane]);
    a0 = fmaf(v, __int_as_float(r.y), a0);
  }
  if (act) Mseg[(size_t)seg * IN_DIM + lane] = f2bf((a0 + a1) + (a2 + a3));
}

// ---------------------------------------------------------------------------
// Stage 2: fused 2-layer MLP with MFMA 16x16x32 bf16.  (unchanged)
// ---------------------------------------------------------------------------
static __device__ __forceinline__ short8 loadM(
    const u16* __restrict__ Mseg, const u16* __restrict__ xb, int m, int k)
{
  short8 r = {0, 0, 0, 0, 0, 0, 0, 0};
  if (k < 96) {
    r = *(const short8*)(Mseg + m * 96 + k);
  } else if (k < K1) {
    r = *(const short8*)(xb + m * IN_DIM + (k - 96));
  }
  return r;
}

__global__ __launch_bounds__(256) void mlp_kernel(
    const u16* __restrict__ Mseg, const u16* __restrict__ xb,
    const u16* __restrict__ W1b, const float* __restrict__ b1,
    const u16* __restrict__ W2b, const float* __restrict__ b2,
    float* __restrict__ out)
{
  __shared__ __align__(16) u16 hbuf[4][32][136];
  const int wave = threadIdx.x >> 6;
  const int lane = threadIdx.x & 63;
  const int col  = lane & 15;
  const int quad = lane >> 4;
  const int kq   = quad * 8;
  const int nodeBase = (blockIdx.x * 4 + wave) * 32;

  const int ma0 = min(nodeBase + col,      N_NODES - 1);
  const int ma1 = min(nodeBase + 16 + col, N_NODES - 1);

  f32x4 acc[2][8];
#pragma unroll
  for (int mt = 0; mt < 2; ++mt)
#pragma unroll
    for (int nt = 0; nt < 8; ++nt) acc[mt][nt] = (f32x4){0.f, 0.f, 0.f, 0.f};

#pragma unroll
  for (int ks = 0; ks < 5; ++ks) {
    const int k = ks * 32 + kq;
    short8 a0 = loadM(Mseg, xb, ma0, k);
    short8 a1 = loadM(Mseg, xb, ma1, k);
#pragma unroll
    for (int nt = 0; nt < 8; ++nt) {
      short8 b = {0, 0, 0, 0, 0, 0, 0, 0};
      if (k < K1)
        b = *(const short8*)(W1b + (nt * 16 + col) * K1 + k);
      acc[0][nt] = __builtin_amdgcn_mfma_f32_16x16x32_bf16(a0, b, acc[0][nt], 0, 0, 0);
      acc[1][nt] = __builtin_amdgcn_mfma_f32_16x16x32_bf16(a1, b, acc[1][nt], 0, 0, 0);
    }
  }

#pragma unroll
  for (int mt = 0; mt < 2; ++mt)
#pragma unroll
    for (int nt = 0; nt < 8; ++nt) {
      const int n = nt * 16 + col;
      const float bb = b1[n];
#pragma unroll
      for (int rg = 0; rg < 4; ++rg) {
        const int rowl = mt * 16 + quad * 4 + rg;
        hbuf[wave][rowl][n] = f2bf(tanhf(acc[mt][nt][rg] + bb));
      }
    }
  __syncthreads();

  f32x4 acc2[2][8];
#pragma unroll
  for (int mt = 0; mt < 2; ++mt)
#pragma unroll
    for (int nt = 0; nt < 8; ++nt) acc2[mt][nt] = (f32x4){0.f, 0.f, 0.f, 0.f};

#pragma unroll
  for (int ks = 0; ks < 4; ++ks) {
    const int k = ks * 32 + kq;
    short8 a0 = *(const short8*)&hbuf[wave][col][k];
    short8 a1 = *(const short8*)&hbuf[wave][16 + col][k];
#pragma unroll
    for (int nt = 0; nt < 8; ++nt) {
      short8 b = *(const short8*)(W2b + (nt * 16 + col) * OUT_DIM + k);
      acc2[0][nt] = __builtin_amdgcn_mfma_f32_16x16x32_bf16(a0, b, acc2[0][nt], 0, 0, 0);
      acc2[1][nt] = __builtin_amdgcn_mfma_f32_16x16x32_bf16(a1, b, acc2[1][nt], 0, 0, 0);
    }
  }

#pragma unroll
  for (int mt = 0; mt < 2; ++mt)
#pragma unroll
    for (int nt = 0; nt < 8; ++nt) {
      const int n = nt * 16 + col;
      const float bb = b2[n];
#pragma unroll
      for (int rg = 0; rg < 4; ++rg) {
        const int node = nodeBase + mt * 16 + quad * 4 + rg;
        if (node < N_NODES)
          out[node * OUT_DIM + n] = tanhf(acc2[mt][nt][rg] + bb);
      }
    }
}

extern "C" void kernel_launch(void* const* d_in, const int* in_sizes, int n_in,
                              void* d_out, int out_size, void* d_ws, size_t ws_size,
                              hipStream_t stream) {
  const float* x   = (const float*)d_in[0];
  const int* eidx  = (const int*)d_in[1];
  const float* ea  = (const float*)d_in[2];
  const float* W1  = (const float*)d_in[3];
  const float* b1  = (const float*)d_in[4];
  const float* W2  = (const float*)d_in[5];
  const float* b2  = (const float*)d_in[6];
  float* out = (float*)d_out;

  // workspace layout (16B-aligned), ~80 MB total:
  char* p = (char*)d_ws;
  u16* Mseg    = (u16*)p;  p += (size_t)NSEG * IN_DIM * 2;        // 19.2 MB
  u16* xb      = (u16*)p;  p += (size_t)N_NODES * IN_DIM * 2;     //  9.6 MB
  u16* W1b     = (u16*)p;  p += OUT_DIM * K1 * 2;
  u16* W2b     = (u16*)p;  p += OUT_DIM * OUT_DIM * 2;
  int* counts  = (int*)p;  p += (size_t)NSUBSEG * 4;              // 12.8 MB
  int* offsets = (int*)p;  p += (size_t)NSUBSEG * 4;              // 12.8 MB
  int* wgsums  = (int*)p;  p += ((NCHUNK + 255) & ~255) * 4;
  int2* csr    = (int2*)p; p += (size_t)NMSG * 8;                 // 25.6 MB

  // zero the histogram counters
  hipMemsetAsync(counts, 0, (size_t)NSUBSEG * 4, stream);

  // conversions
  int prep_elems = OUT_DIM * K1 + OUT_DIM * OUT_DIM;
  prep_w_kernel<<<(prep_elems + 255) / 256, 256, 0, stream>>>(W1, W2, W1b, W2b);
  prep_x_kernel<<<(N_NODES * IN_DIM + 255) / 256, 256, 0, stream>>>(x, xb);

  // CSR build over sub-segment keys
  hist_kernel<<<(N_EDGES + 255) / 256, 256, 0, stream>>>(eidx, counts);
  scan1_kernel<<<NCHUNK, 256, 0, stream>>>(counts, offsets, wgsums);
  scan2_kernel<<<1, 256, 0, stream>>>(wgsums);
  scan3_kernel<<<NCHUNK, 256, 0, stream>>>(offsets, wgsums);
  fill_kernel<<<(N_EDGES + 255) / 256, 256, 0, stream>>>(eidx, ea, offsets, csr);

  // gather: 4 segments per 256-thread block
  gather_kernel<<<NSEG / 4, 256, 0, stream>>>(csr, offsets, xb, Mseg);

  // MLP: 128 nodes per 256-thread block
  int nblocks = (N_NODES + 127) / 128;
  mlp_kernel<<<nblocks, 256, 0, stream>>>(Mseg, xb, W1b, b1, W2b, b2, out);
}

// Round 7
// 376.162 us; speedup vs baseline: 3.5499x; 1.9608x over previous
//
#include <hip/hip_runtime.h>
#include <hip/hip_bf16.h>

#define N_NODES 100000
#define N_EDGES 1600000
#define IN_DIM 48
#define OUT_DIM 128
#define K1 144                 // 3*IN_DIM
#define NSEG (2 * N_NODES)     // 200000 segments (node x {mi,mo})
#define NMSG (2 * N_EDGES)     // 3.2M directed messages
#define NBIN 784               // coarse bins: bin = seg >> 8  (784*256 >= NSEG)
#define BINCAP 4608            // per-bin region capacity: mean 4082 + ~8 sigma
#define EPB 8192               // edges per binscat block

typedef unsigned short u16;
typedef __attribute__((ext_vector_type(8))) short short8;
typedef __attribute__((ext_vector_type(4))) float f32x4;

// round-to-nearest-even f32 -> bf16 bits
static __device__ __forceinline__ u16 f2bf(float f) {
  unsigned u = __float_as_uint(f);
  unsigned r = (u + 0x7fffu + ((u >> 16) & 1u)) >> 16;
  return (u16)r;
}
static __device__ __forceinline__ float bf2f(u16 u) {
  return __uint_as_float(((unsigned)u) << 16);
}

// ---------------------------------------------------------------------------
// Stage 0: dtype conversions (fp32 -> bf16)
// ---------------------------------------------------------------------------
__global__ __launch_bounds__(256) void prep_w_kernel(
    const float* __restrict__ W1, const float* __restrict__ W2,
    u16* __restrict__ W1b, u16* __restrict__ W2b)
{
  int i = blockIdx.x * 256 + threadIdx.x;
  if (i < OUT_DIM * K1) {
    W1b[i] = f2bf(W1[i]);
  } else if (i < OUT_DIM * K1 + OUT_DIM * OUT_DIM) {
    int j = i - OUT_DIM * K1;
    W2b[j] = f2bf(W2[j]);
  }
}

__global__ __launch_bounds__(256) void prep_x_kernel(
    const float* __restrict__ x, u16* __restrict__ xb)
{
  int i = blockIdx.x * 256 + threadIdx.x;
  if (i < N_NODES * IN_DIM) xb[i] = f2bf(x[i]);
}

// ---------------------------------------------------------------------------
// Phase A: binscat — partition 3.2M messages into 784 coarse bins.
// Record (8B): .x = (seg_low << 24) | src, .y = fp32 w bits.
// Block-local LDS hist -> one global atomicAdd per (block,bin) chunk alloc ->
// rank via LDS cursor bump. Each block writes ~21-record contiguous runs.
//   dir0 (mi): dst=col, src=row    dir1 (mo): dst=row, src=col
// ---------------------------------------------------------------------------
__global__ __launch_bounds__(256) void binscat_kernel(
    const int* __restrict__ eidx, const float* __restrict__ ea,
    int* __restrict__ bin_cursor, int2* __restrict__ bkt)
{
  __shared__ int hist[NBIN];   // pass1: counts; then: within-bin write cursor
  for (int i = threadIdx.x; i < NBIN; i += 256) hist[i] = 0;
  __syncthreads();

  const int e0 = blockIdx.x * EPB;
  const int e1 = min(e0 + EPB, N_EDGES);

  // pass 1: block-local histogram
  for (int e = e0 + threadIdx.x; e < e1; e += 256) {
    int row = eidx[e];
    int col = eidx[N_EDGES + e];
    atomicAdd(&hist[col >> 7], 1);              // seg0 = col*2   -> bin seg0>>8
    atomicAdd(&hist[(row * 2 + 1) >> 8], 1);    // seg1 = row*2+1
  }
  __syncthreads();

  // allocate this block's chunk inside each bin's fixed region
  for (int b = threadIdx.x; b < NBIN; b += 256) {
    int c = hist[b];
    hist[b] = c ? atomicAdd(&bin_cursor[b], c) : 0;
  }
  __syncthreads();

  // pass 2: write records
  for (int e = e0 + threadIdx.x; e < e1; e += 256) {
    int row = eidx[e];
    int col = eidx[N_EDGES + e];
    int w = __float_as_int(ea[e]);
    int seg0 = col * 2;
    int seg1 = row * 2 + 1;
    int s0 = atomicAdd(&hist[seg0 >> 8], 1);
    if (s0 < BINCAP)
      bkt[(size_t)(seg0 >> 8) * BINCAP + s0] =
          make_int2(((seg0 & 255) << 24) | row, w);
    int s1 = atomicAdd(&hist[seg1 >> 8], 1);
    if (s1 < BINCAP)
      bkt[(size_t)(seg1 >> 8) * BINCAP + s1] =
          make_int2(((seg1 & 255) << 24) | col, w);
  }
}

// ---------------------------------------------------------------------------
// binscan: 1-block exclusive scan of the 784 bin counts -> bin_base
// ---------------------------------------------------------------------------
__global__ __launch_bounds__(256) void binscan_kernel(
    const int* __restrict__ bin_cursor, int* __restrict__ bin_base)
{
  __shared__ int sh[256];
  int carry = 0;
  for (int base = 0; base < NBIN; base += 256) {
    int idx = base + threadIdx.x;
    int v = (idx < NBIN) ? min(bin_cursor[idx], BINCAP) : 0;
    sh[threadIdx.x] = v;
    __syncthreads();
#pragma unroll
    for (int off = 1; off < 256; off <<= 1) {
      int t = (threadIdx.x >= off) ? sh[threadIdx.x - off] : 0;
      __syncthreads();
      sh[threadIdx.x] += t;
      __syncthreads();
    }
    if (idx < NBIN) bin_base[idx] = carry + (threadIdx.x ? sh[threadIdx.x - 1] : 0);
    carry += sh[255];
    __syncthreads();
  }
}

// ---------------------------------------------------------------------------
// Phase B: binsort — one block per bin. LDS hist over the bin's 256 segments,
// LDS scan, write exact per-segment offsets + 4B-packed CSR
// (rec = src<<15 | w_bf16_lo15; ea >= 0 so the bf16 sign bit is always 0).
// All CSR writes land in the bin's contiguous range -> no write amplification.
// ---------------------------------------------------------------------------
__global__ __launch_bounds__(256) void binsort_kernel(
    const int2* __restrict__ bkt, const int* __restrict__ bin_cursor,
    const int* __restrict__ bin_base, unsigned* __restrict__ csr,
    int* __restrict__ offsets)
{
  __shared__ int hist[256];
  __shared__ int sh[256];
  const int b = blockIdx.x;
  const int cnt = min(bin_cursor[b], BINCAP);
  const int2* recs = bkt + (size_t)b * BINCAP;
  const int t = threadIdx.x;

  hist[t] = 0;
  __syncthreads();
  for (int j = t; j < cnt; j += 256)
    atomicAdd(&hist[(unsigned)recs[j].x >> 24], 1);
  __syncthreads();

  // exclusive scan of hist[256]
  sh[t] = hist[t];
  __syncthreads();
#pragma unroll
  for (int off = 1; off < 256; off <<= 1) {
    int v = (t >= off) ? sh[t - off] : 0;
    __syncthreads();
    sh[t] += v;
    __syncthreads();
  }
  const int base = bin_base[b];
  const int excl = base + (t ? sh[t - 1] : 0);
  offsets[b * 256 + t] = excl;   // pad segments get excl == segment end; fine
  hist[t] = excl;                // becomes the write cursor
  __syncthreads();

  for (int j = t; j < cnt; j += 256) {
    int2 r = recs[j];
    int segl = (unsigned)r.x >> 24;
    unsigned src = (unsigned)r.x & 0xFFFFFFu;
    unsigned wb = f2bf(__int_as_float(r.y));
    int slot = atomicAdd(&hist[segl], 1);
    csr[slot] = (src << 15) | (wb & 0x7FFFu);
  }
}

// ---------------------------------------------------------------------------
// Gather: one wave per segment; lanes 0..47 = dims. Unroll-4 with 4
// independent accumulators -> 4 x-row loads in flight. 4B packed records.
// Mseg layout: [node][0..47]=mi, [48..95]=mo (bf16)
// ---------------------------------------------------------------------------
__global__ __launch_bounds__(256) void gather_kernel(
    const unsigned* __restrict__ csr, const int* __restrict__ offs,
    const u16* __restrict__ xb, u16* __restrict__ Mseg)
{
  int seg = blockIdx.x * 4 + (threadIdx.x >> 6);
  int lane = threadIdx.x & 63;
  int beg = offs[seg];
  int end = offs[seg + 1];
  bool act = lane < IN_DIM;
  float a0 = 0.f, a1 = 0.f, a2 = 0.f, a3 = 0.f;
  int j = beg;
  for (; j + 4 <= end; j += 4) {
    unsigned r0 = csr[j + 0];
    unsigned r1 = csr[j + 1];
    unsigned r2 = csr[j + 2];
    unsigned r3 = csr[j + 3];
    float v0 = 0.f, v1 = 0.f, v2 = 0.f, v3 = 0.f;
    if (act) {
      v0 = bf2f(xb[(r0 >> 15) * IN_DIM + lane]);
      v1 = bf2f(xb[(r1 >> 15) * IN_DIM + lane]);
      v2 = bf2f(xb[(r2 >> 15) * IN_DIM + lane]);
      v3 = bf2f(xb[(r3 >> 15) * IN_DIM + lane]);
    }
    a0 = fmaf(v0, bf2f((u16)(r0 & 0x7FFFu)), a0);
    a1 = fmaf(v1, bf2f((u16)(r1 & 0x7FFFu)), a1);
    a2 = fmaf(v2, bf2f((u16)(r2 & 0x7FFFu)), a2);
    a3 = fmaf(v3, bf2f((u16)(r3 & 0x7FFFu)), a3);
  }
  for (; j < end; ++j) {
    unsigned r = csr[j];
    float v = 0.f;
    if (act) v = bf2f(xb[(r >> 15) * IN_DIM + lane]);
    a0 = fmaf(v, bf2f((u16)(r & 0x7FFFu)), a0);
  }
  if (act) Mseg[(size_t)seg * IN_DIM + lane] = f2bf((a0 + a1) + (a2 + a3));
}

// ---------------------------------------------------------------------------
// Stage 2: fused 2-layer MLP with MFMA 16x16x32 bf16.  (unchanged)
// ---------------------------------------------------------------------------
static __device__ __forceinline__ short8 loadM(
    const u16* __restrict__ Mseg, const u16* __restrict__ xb, int m, int k)
{
  short8 r = {0, 0, 0, 0, 0, 0, 0, 0};
  if (k < 96) {
    r = *(const short8*)(Mseg + m * 96 + k);
  } else if (k < K1) {
    r = *(const short8*)(xb + m * IN_DIM + (k - 96));
  }
  return r;
}

__global__ __launch_bounds__(256) void mlp_kernel(
    const u16* __restrict__ Mseg, const u16* __restrict__ xb,
    const u16* __restrict__ W1b, const float* __restrict__ b1,
    const u16* __restrict__ W2b, const float* __restrict__ b2,
    float* __restrict__ out)
{
  __shared__ __align__(16) u16 hbuf[4][32][136];
  const int wave = threadIdx.x >> 6;
  const int lane = threadIdx.x & 63;
  const int col  = lane & 15;
  const int quad = lane >> 4;
  const int kq   = quad * 8;
  const int nodeBase = (blockIdx.x * 4 + wave) * 32;

  const int ma0 = min(nodeBase + col,      N_NODES - 1);
  const int ma1 = min(nodeBase + 16 + col, N_NODES - 1);

  f32x4 acc[2][8];
#pragma unroll
  for (int mt = 0; mt < 2; ++mt)
#pragma unroll
    for (int nt = 0; nt < 8; ++nt) acc[mt][nt] = (f32x4){0.f, 0.f, 0.f, 0.f};

#pragma unroll
  for (int ks = 0; ks < 5; ++ks) {
    const int k = ks * 32 + kq;
    short8 a0 = loadM(Mseg, xb, ma0, k);
    short8 a1 = loadM(Mseg, xb, ma1, k);
#pragma unroll
    for (int nt = 0; nt < 8; ++nt) {
      short8 b = {0, 0, 0, 0, 0, 0, 0, 0};
      if (k < K1)
        b = *(const short8*)(W1b + (nt * 16 + col) * K1 + k);
      acc[0][nt] = __builtin_amdgcn_mfma_f32_16x16x32_bf16(a0, b, acc[0][nt], 0, 0, 0);
      acc[1][nt] = __builtin_amdgcn_mfma_f32_16x16x32_bf16(a1, b, acc[1][nt], 0, 0, 0);
    }
  }

#pragma unroll
  for (int mt = 0; mt < 2; ++mt)
#pragma unroll
    for (int nt = 0; nt < 8; ++nt) {
      const int n = nt * 16 + col;
      const float bb = b1[n];
#pragma unroll
      for (int rg = 0; rg < 4; ++rg) {
        const int rowl = mt * 16 + quad * 4 + rg;
        hbuf[wave][rowl][n] = f2bf(tanhf(acc[mt][nt][rg] + bb));
      }
    }
  __syncthreads();

  f32x4 acc2[2][8];
#pragma unroll
  for (int mt = 0; mt < 2; ++mt)
#pragma unroll
    for (int nt = 0; nt < 8; ++nt) acc2[mt][nt] = (f32x4){0.f, 0.f, 0.f, 0.f};

#pragma unroll
  for (int ks = 0; ks < 4; ++ks) {
    const int k = ks * 32 + kq;
    short8 a0 = *(const short8*)&hbuf[wave][col][k];
    short8 a1 = *(const short8*)&hbuf[wave][16 + col][k];
#pragma unroll
    for (int nt = 0; nt < 8; ++nt) {
      short8 b = *(const short8*)(W2b + (nt * 16 + col) * OUT_DIM + k);
      acc2[0][nt] = __builtin_amdgcn_mfma_f32_16x16x32_bf16(a0, b, acc2[0][nt], 0, 0, 0);
      acc2[1][nt] = __builtin_amdgcn_mfma_f32_16x16x32_bf16(a1, b, acc2[1][nt], 0, 0, 0);
    }
  }

#pragma unroll
  for (int mt = 0; mt < 2; ++mt)
#pragma unroll
    for (int nt = 0; nt < 8; ++nt) {
      const int n = nt * 16 + col;
      const float bb = b2[n];
#pragma unroll
      for (int rg = 0; rg < 4; ++rg) {
        const int node = nodeBase + mt * 16 + quad * 4 + rg;
        if (node < N_NODES)
          out[node * OUT_DIM + n] = tanhf(acc2[mt][nt][rg] + bb);
      }
    }
}

extern "C" void kernel_launch(void* const* d_in, const int* in_sizes, int n_in,
                              void* d_out, int out_size, void* d_ws, size_t ws_size,
                              hipStream_t stream) {
  const float* x   = (const float*)d_in[0];
  const int* eidx  = (const int*)d_in[1];
  const float* ea  = (const float*)d_in[2];
  const float* W1  = (const float*)d_in[3];
  const float* b1  = (const float*)d_in[4];
  const float* W2  = (const float*)d_in[5];
  const float* b2  = (const float*)d_in[6];
  float* out = (float*)d_out;

  // workspace layout (16B-aligned), ~71 MB total:
  char* p = (char*)d_ws;
  u16* Mseg       = (u16*)p;      p += (size_t)NSEG * IN_DIM * 2;      // 19.2 MB
  u16* xb         = (u16*)p;      p += (size_t)N_NODES * IN_DIM * 2;   //  9.6 MB
  u16* W1b        = (u16*)p;      p += OUT_DIM * K1 * 2;
  u16* W2b        = (u16*)p;      p += OUT_DIM * OUT_DIM * 2;
  int* bin_cursor = (int*)p;      p += 1024 * 4;
  int* bin_base   = (int*)p;      p += 1024 * 4;
  int* offsets    = (int*)p;      p += (size_t)(NBIN * 256 + 16) * 4;  //  0.8 MB
  int2* bkt       = (int2*)p;     p += (size_t)NBIN * BINCAP * 8;      // 28.9 MB
  unsigned* csr   = (unsigned*)p; p += (size_t)NMSG * 4;               // 12.8 MB

  // zero the bin cursors only
  hipMemsetAsync(bin_cursor, 0, 1024 * 4, stream);

  // conversions
  int prep_elems = OUT_DIM * K1 + OUT_DIM * OUT_DIM;
  prep_w_kernel<<<(prep_elems + 255) / 256, 256, 0, stream>>>(W1, W2, W1b, W2b);
  prep_x_kernel<<<(N_NODES * IN_DIM + 255) / 256, 256, 0, stream>>>(x, xb);

  // two-level binning
  binscat_kernel<<<(N_EDGES + EPB - 1) / EPB, 256, 0, stream>>>(
      eidx, ea, bin_cursor, bkt);
  binscan_kernel<<<1, 256, 0, stream>>>(bin_cursor, bin_base);
  binsort_kernel<<<NBIN, 256, 0, stream>>>(bkt, bin_cursor, bin_base, csr, offsets);

  // gather: 4 segments per 256-thread block
  gather_kernel<<<NSEG / 4, 256, 0, stream>>>(csr, offsets, xb, Mseg);

  // MLP: 128 nodes per 256-thread block
  int nblocks = (N_NODES + 127) / 128;
  mlp_kernel<<<nblocks, 256, 0, stream>>>(Mseg, xb, W1b, b1, W2b, b2, out);
}

// Round 8
// 306.563 us; speedup vs baseline: 4.3558x; 1.2270x over previous
//
#include <hip/hip_runtime.h>
#include <hip/hip_bf16.h>

#define N_NODES 100000
#define N_EDGES 1600000
#define IN_DIM 48
#define OUT_DIM 128
#define K1 144                 // 3*IN_DIM
#define NSEG (2 * N_NODES)     // 200000 segments (node x {mi,mo})
#define NMSG (2 * N_EDGES)     // 3.2M directed messages
#define NBIN 784               // coarse bins: bin = seg >> 8  (784*256 >= NSEG)
#define BINCAP 4608            // per-bin region capacity: mean 4082 + ~8 sigma
#define EPB 4096               // edges per binscat block (391 blocks ~ 1.5/CU)

typedef unsigned short u16;
typedef unsigned long long u64;
typedef __attribute__((ext_vector_type(8))) short short8;
typedef __attribute__((ext_vector_type(4))) float f32x4;

// round-to-nearest-even f32 -> bf16 bits
static __device__ __forceinline__ u16 f2bf(float f) {
  unsigned u = __float_as_uint(f);
  unsigned r = (u + 0x7fffu + ((u >> 16) & 1u)) >> 16;
  return (u16)r;
}
static __device__ __forceinline__ float bf2f(u16 u) {
  return __uint_as_float(((unsigned)u) << 16);
}
// fast tanh: 1 - 2/(e^{2x}+1)  (v_exp_f32 + v_rcp_f32, ~1e-6 abs error)
static __device__ __forceinline__ float ftanh(float x) {
  return 1.f - 2.f * __builtin_amdgcn_rcpf(__expf(2.f * x) + 1.f);
}

// ---------------------------------------------------------------------------
// Stage 0: dtype conversions (fp32 -> bf16)
// ---------------------------------------------------------------------------
__global__ __launch_bounds__(256) void prep_w_kernel(
    const float* __restrict__ W1, const float* __restrict__ W2,
    u16* __restrict__ W1b, u16* __restrict__ W2b)
{
  int i = blockIdx.x * 256 + threadIdx.x;
  if (i < OUT_DIM * K1) {
    W1b[i] = f2bf(W1[i]);
  } else if (i < OUT_DIM * K1 + OUT_DIM * OUT_DIM) {
    int j = i - OUT_DIM * K1;
    W2b[j] = f2bf(W2[j]);
  }
}

__global__ __launch_bounds__(256) void prep_x_kernel(
    const float* __restrict__ x, u16* __restrict__ xb)
{
  int i = blockIdx.x * 256 + threadIdx.x;
  if (i < N_NODES * IN_DIM) xb[i] = f2bf(x[i]);
}

// ---------------------------------------------------------------------------
// Phase A: binscat — partition 3.2M messages into 784 coarse bins.
// Record (8B): .x = (seg_low << 24) | src, .y = fp32 w bits.
//   dir0 (mi): dst=col, src=row    dir1 (mo): dst=row, src=col
// ---------------------------------------------------------------------------
__global__ __launch_bounds__(256) void binscat_kernel(
    const int* __restrict__ eidx, const float* __restrict__ ea,
    int* __restrict__ bin_cursor, int2* __restrict__ bkt)
{
  __shared__ int hist[NBIN];   // pass1: counts; then: within-bin write cursor
  for (int i = threadIdx.x; i < NBIN; i += 256) hist[i] = 0;
  __syncthreads();

  const int e0 = blockIdx.x * EPB;
  const int e1 = min(e0 + EPB, N_EDGES);

  for (int e = e0 + threadIdx.x; e < e1; e += 256) {
    int row = eidx[e];
    int col = eidx[N_EDGES + e];
    atomicAdd(&hist[col >> 7], 1);              // seg0 = col*2   -> bin seg0>>8
    atomicAdd(&hist[(row * 2 + 1) >> 8], 1);    // seg1 = row*2+1
  }
  __syncthreads();

  for (int b = threadIdx.x; b < NBIN; b += 256) {
    int c = hist[b];
    hist[b] = c ? atomicAdd(&bin_cursor[b], c) : 0;
  }
  __syncthreads();

  for (int e = e0 + threadIdx.x; e < e1; e += 256) {
    int row = eidx[e];
    int col = eidx[N_EDGES + e];
    int w = __float_as_int(ea[e]);
    int seg0 = col * 2;
    int seg1 = row * 2 + 1;
    int s0 = atomicAdd(&hist[seg0 >> 8], 1);
    if (s0 < BINCAP)
      bkt[(size_t)(seg0 >> 8) * BINCAP + s0] =
          make_int2(((seg0 & 255) << 24) | row, w);
    int s1 = atomicAdd(&hist[seg1 >> 8], 1);
    if (s1 < BINCAP)
      bkt[(size_t)(seg1 >> 8) * BINCAP + s1] =
          make_int2(((seg1 & 255) << 24) | col, w);
  }
}

// ---------------------------------------------------------------------------
// binscan: 1-block exclusive scan of the 784 bin counts -> bin_base
// ---------------------------------------------------------------------------
__global__ __launch_bounds__(256) void binscan_kernel(
    const int* __restrict__ bin_cursor, int* __restrict__ bin_base)
{
  __shared__ int sh[256];
  int carry = 0;
  for (int base = 0; base < NBIN; base += 256) {
    int idx = base + threadIdx.x;
    int v = (idx < NBIN) ? min(bin_cursor[idx], BINCAP) : 0;
    sh[threadIdx.x] = v;
    __syncthreads();
#pragma unroll
    for (int off = 1; off < 256; off <<= 1) {
      int t = (threadIdx.x >= off) ? sh[threadIdx.x - off] : 0;
      __syncthreads();
      sh[threadIdx.x] += t;
      __syncthreads();
    }
    if (idx < NBIN) bin_base[idx] = carry + (threadIdx.x ? sh[threadIdx.x - 1] : 0);
    carry += sh[255];
    __syncthreads();
  }
}

// ---------------------------------------------------------------------------
// Phase B: binsort — one block per bin. LDS hist over the bin's 256 segments,
// LDS scan, write exact per-segment offsets + 4B-packed CSR
// (rec = src<<15 | w_bf16_lo15; ea >= 0 so the bf16 sign bit is always 0).
// ---------------------------------------------------------------------------
__global__ __launch_bounds__(256) void binsort_kernel(
    const int2* __restrict__ bkt, const int* __restrict__ bin_cursor,
    const int* __restrict__ bin_base, unsigned* __restrict__ csr,
    int* __restrict__ offsets)
{
  __shared__ int hist[256];
  __shared__ int sh[256];
  const int b = blockIdx.x;
  const int cnt = min(bin_cursor[b], BINCAP);
  const int2* recs = bkt + (size_t)b * BINCAP;
  const int t = threadIdx.x;

  hist[t] = 0;
  __syncthreads();
  for (int j = t; j < cnt; j += 256)
    atomicAdd(&hist[(unsigned)recs[j].x >> 24], 1);
  __syncthreads();

  sh[t] = hist[t];
  __syncthreads();
#pragma unroll
  for (int off = 1; off < 256; off <<= 1) {
    int v = (t >= off) ? sh[t - off] : 0;
    __syncthreads();
    sh[t] += v;
    __syncthreads();
  }
  const int base = bin_base[b];
  const int excl = base + (t ? sh[t - 1] : 0);
  offsets[b * 256 + t] = excl;
  hist[t] = excl;
  __syncthreads();

  for (int j = t; j < cnt; j += 256) {
    int2 r = recs[j];
    int segl = (unsigned)r.x >> 24;
    unsigned src = (unsigned)r.x & 0xFFFFFFu;
    unsigned wb = f2bf(__int_as_float(r.y));
    int slot = atomicAdd(&hist[segl], 1);
    csr[slot] = (src << 15) | (wb & 0x7FFFu);
  }
}

// ---------------------------------------------------------------------------
// Gather: one wave per segment. 12 lanes per record (u64 = 4 dims each),
// 5 records per load instruction (lanes 0..59, group g = lane/12).
// 3-shuffle cross-group reduce once per segment; lanes 0..11 write 8B each.
// Mseg layout: [node][0..47]=mi, [48..95]=mo (bf16)
// ---------------------------------------------------------------------------
__global__ __launch_bounds__(256) void gather_kernel(
    const unsigned* __restrict__ csr, const int* __restrict__ offs,
    const u64* __restrict__ xb64, u16* __restrict__ Mseg)
{
  const int seg  = blockIdx.x * 4 + (threadIdx.x >> 6);
  const int lane = threadIdx.x & 63;
  const int g    = lane / 12;          // record group 0..4 (5: idle lanes 60-63)
  const int r12  = lane - g * 12;      // word index within the row (0..11)
  const bool gact = g < 5;
  const int gi   = gact ? g : 0;

  const int beg = offs[seg];
  const int end = offs[seg + 1];

  f32x4 ap = {0.f, 0.f, 0.f, 0.f};
  f32x4 aq = {0.f, 0.f, 0.f, 0.f};

  int j = beg;
  for (; j + 10 <= end; j += 10) {
    unsigned rp = csr[j + gi];
    unsigned rq = csr[j + 5 + gi];
    u64 vp = xb64[(size_t)(rp >> 15) * 12 + r12];
    u64 vq = xb64[(size_t)(rq >> 15) * 12 + r12];
    float wp = __uint_as_float((rp & 0x7FFFu) << 16);
    float wq = __uint_as_float((rq & 0x7FFFu) << 16);
    unsigned pl = (unsigned)vp, ph = (unsigned)(vp >> 32);
    unsigned ql = (unsigned)vq, qh = (unsigned)(vq >> 32);
    ap[0] = fmaf(__uint_as_float(pl << 16), wp, ap[0]);
    ap[1] = fmaf(__uint_as_float(pl & 0xFFFF0000u), wp, ap[1]);
    ap[2] = fmaf(__uint_as_float(ph << 16), wp, ap[2]);
    ap[3] = fmaf(__uint_as_float(ph & 0xFFFF0000u), wp, ap[3]);
    aq[0] = fmaf(__uint_as_float(ql << 16), wq, aq[0]);
    aq[1] = fmaf(__uint_as_float(ql & 0xFFFF0000u), wq, aq[1]);
    aq[2] = fmaf(__uint_as_float(qh << 16), wq, aq[2]);
    aq[3] = fmaf(__uint_as_float(qh & 0xFFFF0000u), wq, aq[3]);
  }
  for (; j < end; j += 5) {
    int cnt = end - j;                       // 1..5 (or full 5)
    bool act = gact && (g < cnt);
    unsigned r = csr[j + (act ? g : 0)];
    u64 v = xb64[(size_t)(r >> 15) * 12 + r12];
    float w = act ? __uint_as_float((r & 0x7FFFu) << 16) : 0.f;
    unsigned lo = (unsigned)v, hi = (unsigned)(v >> 32);
    ap[0] = fmaf(__uint_as_float(lo << 16), w, ap[0]);
    ap[1] = fmaf(__uint_as_float(lo & 0xFFFF0000u), w, ap[1]);
    ap[2] = fmaf(__uint_as_float(hi << 16), w, ap[2]);
    ap[3] = fmaf(__uint_as_float(hi & 0xFFFF0000u), w, ap[3]);
  }

  f32x4 a;
#pragma unroll
  for (int c = 0; c < 4; ++c) a[c] = ap[c] + aq[c];
  // reduce groups: lanes 0-11 end with g0+g1+g2+g3+g4
#pragma unroll
  for (int c = 0; c < 4; ++c) {
    float s1 = a[c] + __shfl(a[c], lane + 12, 64);   // g0+g1 (also g2+g3 @24-35)
    float s2 = s1 + __shfl(s1, lane + 24, 64);       // g0..g3 @0-11
    a[c] = s2 + __shfl(a[c], lane + 48, 64);         // + g4
  }

  if (lane < 12) {
    unsigned w0 = (unsigned)f2bf(a[0]) | ((unsigned)f2bf(a[1]) << 16);
    unsigned w1 = (unsigned)f2bf(a[2]) | ((unsigned)f2bf(a[3]) << 16);
    unsigned* dst = (unsigned*)(Mseg + (size_t)seg * IN_DIM) + lane * 2;
    dst[0] = w0;
    dst[1] = w1;
  }
}

// ---------------------------------------------------------------------------
// Stage 2: fused 2-layer MLP with MFMA 16x16x32 bf16.
// ---------------------------------------------------------------------------
static __device__ __forceinline__ short8 loadM(
    const u16* __restrict__ Mseg, const u16* __restrict__ xb, int m, int k)
{
  short8 r = {0, 0, 0, 0, 0, 0, 0, 0};
  if (k < 96) {
    r = *(const short8*)(Mseg + m * 96 + k);
  } else if (k < K1) {
    r = *(const short8*)(xb + m * IN_DIM + (k - 96));
  }
  return r;
}

__global__ __launch_bounds__(256) void mlp_kernel(
    const u16* __restrict__ Mseg, const u16* __restrict__ xb,
    const u16* __restrict__ W1b, const float* __restrict__ b1,
    const u16* __restrict__ W2b, const float* __restrict__ b2,
    float* __restrict__ out)
{
  __shared__ __align__(16) u16 hbuf[4][32][136];
  const int wave = threadIdx.x >> 6;
  const int lane = threadIdx.x & 63;
  const int col  = lane & 15;
  const int quad = lane >> 4;
  const int kq   = quad * 8;
  const int nodeBase = (blockIdx.x * 4 + wave) * 32;

  const int ma0 = min(nodeBase + col,      N_NODES - 1);
  const int ma1 = min(nodeBase + 16 + col, N_NODES - 1);

  f32x4 acc[2][8];
#pragma unroll
  for (int mt = 0; mt < 2; ++mt)
#pragma unroll
    for (int nt = 0; nt < 8; ++nt) acc[mt][nt] = (f32x4){0.f, 0.f, 0.f, 0.f};

#pragma unroll
  for (int ks = 0; ks < 5; ++ks) {
    const int k = ks * 32 + kq;
    short8 a0 = loadM(Mseg, xb, ma0, k);
    short8 a1 = loadM(Mseg, xb, ma1, k);
#pragma unroll
    for (int nt = 0; nt < 8; ++nt) {
      short8 b = {0, 0, 0, 0, 0, 0, 0, 0};
      if (k < K1)
        b = *(const short8*)(W1b + (nt * 16 + col) * K1 + k);
      acc[0][nt] = __builtin_amdgcn_mfma_f32_16x16x32_bf16(a0, b, acc[0][nt], 0, 0, 0);
      acc[1][nt] = __builtin_amdgcn_mfma_f32_16x16x32_bf16(a1, b, acc[1][nt], 0, 0, 0);
    }
  }

#pragma unroll
  for (int mt = 0; mt < 2; ++mt)
#pragma unroll
    for (int nt = 0; nt < 8; ++nt) {
      const int n = nt * 16 + col;
      const float bb = b1[n];
#pragma unroll
      for (int rg = 0; rg < 4; ++rg) {
        const int rowl = mt * 16 + quad * 4 + rg;
        hbuf[wave][rowl][n] = f2bf(ftanh(acc[mt][nt][rg] + bb));
      }
    }
  __syncthreads();

  f32x4 acc2[2][8];
#pragma unroll
  for (int mt = 0; mt < 2; ++mt)
#pragma unroll
    for (int nt = 0; nt < 8; ++nt) acc2[mt][nt] = (f32x4){0.f, 0.f, 0.f, 0.f};

#pragma unroll
  for (int ks = 0; ks < 4; ++ks) {
    const int k = ks * 32 + kq;
    short8 a0 = *(const short8*)&hbuf[wave][col][k];
    short8 a1 = *(const short8*)&hbuf[wave][16 + col][k];
#pragma unroll
    for (int nt = 0; nt < 8; ++nt) {
      short8 b = *(const short8*)(W2b + (nt * 16 + col) * OUT_DIM + k);
      acc2[0][nt] = __builtin_amdgcn_mfma_f32_16x16x32_bf16(a0, b, acc2[0][nt], 0, 0, 0);
      acc2[1][nt] = __builtin_amdgcn_mfma_f32_16x16x32_bf16(a1, b, acc2[1][nt], 0, 0, 0);
    }
  }

#pragma unroll
  for (int mt = 0; mt < 2; ++mt)
#pragma unroll
    for (int nt = 0; nt < 8; ++nt) {
      const int n = nt * 16 + col;
      const float bb = b2[n];
#pragma unroll
      for (int rg = 0; rg < 4; ++rg) {
        const int node = nodeBase + mt * 16 + quad * 4 + rg;
        if (node < N_NODES)
          out[node * OUT_DIM + n] = ftanh(acc2[mt][nt][rg] + bb);
      }
    }
}

extern "C" void kernel_launch(void* const* d_in, const int* in_sizes, int n_in,
                              void* d_out, int out_size, void* d_ws, size_t ws_size,
                              hipStream_t stream) {
  const float* x   = (const float*)d_in[0];
  const int* eidx  = (const int*)d_in[1];
  const float* ea  = (const float*)d_in[2];
  const float* W1  = (const float*)d_in[3];
  const float* b1  = (const float*)d_in[4];
  const float* W2  = (const float*)d_in[5];
  const float* b2  = (const float*)d_in[6];
  float* out = (float*)d_out;

  // workspace layout (16B-aligned), ~71 MB total:
  char* p = (char*)d_ws;
  u16* Mseg       = (u16*)p;      p += (size_t)NSEG * IN_DIM * 2;      // 19.2 MB
  u16* xb         = (u16*)p;      p += (size_t)N_NODES * IN_DIM * 2;   //  9.6 MB
  u16* W1b        = (u16*)p;      p += OUT_DIM * K1 * 2;
  u16* W2b        = (u16*)p;      p += OUT_DIM * OUT_DIM * 2;
  int* bin_cursor = (int*)p;      p += 1024 * 4;
  int* bin_base   = (int*)p;      p += 1024 * 4;
  int* offsets    = (int*)p;      p += (size_t)(NBIN * 256 + 16) * 4;  //  0.8 MB
  int2* bkt       = (int2*)p;     p += (size_t)NBIN * BINCAP * 8;      // 28.9 MB
  unsigned* csr   = (unsigned*)p; p += (size_t)NMSG * 4;               // 12.8 MB

  hipMemsetAsync(bin_cursor, 0, 1024 * 4, stream);

  int prep_elems = OUT_DIM * K1 + OUT_DIM * OUT_DIM;
  prep_w_kernel<<<(prep_elems + 255) / 256, 256, 0, stream>>>(W1, W2, W1b, W2b);
  prep_x_kernel<<<(N_NODES * IN_DIM + 255) / 256, 256, 0, stream>>>(x, xb);

  binscat_kernel<<<(N_EDGES + EPB - 1) / EPB, 256, 0, stream>>>(
      eidx, ea, bin_cursor, bkt);
  binscan_kernel<<<1, 256, 0, stream>>>(bin_cursor, bin_base);
  binsort_kernel<<<NBIN, 256, 0, stream>>>(bkt, bin_cursor, bin_base, csr, offsets);

  gather_kernel<<<NSEG / 4, 256, 0, stream>>>(csr, offsets, (const u64*)xb, Mseg);

  int nblocks = (N_NODES + 127) / 128;
  mlp_kernel<<<nblocks, 256, 0, stream>>>(Mseg, xb, W1b, b1, W2b, b2, out);
}